// Round 8
// baseline (266.496 us; speedup 1.0000x reference)
//
#include <hip/hip_runtime.h>

typedef __bf16 bf16x8 __attribute__((ext_vector_type(8)));
typedef float f32x4 __attribute__((ext_vector_type(4)));
typedef unsigned short u16;

#define D_MODEL 1024
#define SEQ     2048
#define BATCH   4
#define NH      16
#define DH      64

static __device__ __forceinline__ u16 f2bf(float f) {
    union { float f; unsigned u; } v; v.f = f;
    unsigned r = v.u + 0x7FFF + ((v.u >> 16) & 1);  // RNE
    return (u16)(r >> 16);
}
static __device__ __forceinline__ void storeC(u16* C, size_t off, float v) { C[off] = f2bf(v); }
static __device__ __forceinline__ void storeC(float* C, size_t off, float v) { C[off] = v; }

// async global->LDS, 16 B per lane; lds must be wave-uniform base
static __device__ __forceinline__ void async_ld16(u16* lds, const u16* g) {
    __builtin_amdgcn_global_load_lds(
        (const __attribute__((address_space(1))) unsigned int*)g,
        (__attribute__((address_space(3))) unsigned int*)lds, 16, 0, 0);
}

// ---------------------------------------------------------------------------
// Prepass: fp32 -> bf16 convert (8 elems/thread)
// ---------------------------------------------------------------------------
__global__ __launch_bounds__(256) void cvt_bf16(const float* __restrict__ in,
                                                u16* __restrict__ out) {
    size_t i = ((size_t)blockIdx.x * 256 + threadIdx.x) * 8;
    float4 a = *(const float4*)(in + i);
    float4 b = *(const float4*)(in + i + 4);
    u16 t[8] = {f2bf(a.x), f2bf(a.y), f2bf(a.z), f2bf(a.w),
                f2bf(b.x), f2bf(b.y), f2bf(b.z), f2bf(b.w)};
    *(uint4*)(out + i) = *(uint4*)t;
}

// ---------------------------------------------------------------------------
// Prepass: W [K][N] fp32 -> Wt [N][K] bf16
// ---------------------------------------------------------------------------
__global__ void transpose_w(const float* __restrict__ in, u16* __restrict__ out,
                            int K, int N) {
    __shared__ float tile[32][33];
    int n0 = blockIdx.x * 32, k0 = blockIdx.y * 32;
    int tx = threadIdx.x, ty = threadIdx.y;
    for (int i = ty; i < 32; i += 8)
        tile[i][tx] = in[(size_t)(k0 + i) * N + n0 + tx];
    __syncthreads();
    for (int i = ty; i < 32; i += 8)
        out[(size_t)(n0 + i) * K + k0 + tx] = f2bf(tile[tx][i]);
}

// ---------------------------------------------------------------------------
// Output projection GEMM, 128x64 tile (M x N), BK=64, grid (M/128, N/64).
// 2x more blocks than 128x128 at N=1024 -> 4 blocks/CU (TLP for the
// barrier-drain overlap). Waves 2x2: each computes 64x32 (4x2 accs).
// ---------------------------------------------------------------------------
__global__ __launch_bounds__(256) void gemm_bt_n64(
    const u16* __restrict__ A, int lda,
    const u16* __restrict__ Bt, int ldb,
    const float* __restrict__ bias,
    float* __restrict__ C, int ldc, int K) {
    __shared__ u16 As[128 * 64];   // [row][slot8*8], swizzled
    __shared__ u16 Bs[64 * 64];
    int m0 = blockIdx.x * 128, n0 = blockIdx.y * 64;
    int tid = threadIdx.x;
    int w = tid >> 6, lane = tid & 63, l15 = lane & 15, g = lane >> 4;
    int wm = (w & 1) * 64, wn = (w >> 1) * 32;
    int srow = w * 8 + (lane >> 3);      // [0,32)
    int sk8  = lane & 7;

    f32x4 acc[4][2] = {};
    for (int kt = 0; kt < K; kt += 64) {
        #pragma unroll
        for (int p = 0; p < 4; ++p) {
            int row = p * 32 + srow;
            int k8 = sk8 ^ (row & 7);
            async_ld16(&As[p * 2048 + w * 512],
                       A + (size_t)(m0 + row) * lda + kt + k8 * 8);
        }
        #pragma unroll
        for (int p = 0; p < 2; ++p) {
            int row = p * 32 + srow;
            int k8 = sk8 ^ (row & 7);
            async_ld16(&Bs[p * 2048 + w * 512],
                       Bt + (size_t)(n0 + row) * ldb + kt + k8 * 8);
        }
        __syncthreads();
        #pragma unroll
        for (int kk = 0; kk < 2; ++kk) {
            bf16x8 af[4], bf_[2];
            int s8 = ((kk << 2) | g) ^ (l15 & 7);
            #pragma unroll
            for (int i = 0; i < 4; ++i)
                af[i]  = *(const bf16x8*)&As[(wm + i * 16 + l15) * 64 + s8 * 8];
            #pragma unroll
            for (int j = 0; j < 2; ++j)
                bf_[j] = *(const bf16x8*)&Bs[(wn + j * 16 + l15) * 64 + s8 * 8];
            #pragma unroll
            for (int i = 0; i < 4; ++i)
                #pragma unroll
                for (int j = 0; j < 2; ++j)
                    acc[i][j] = __builtin_amdgcn_mfma_f32_16x16x32_bf16(
                        af[i], bf_[j], acc[i][j], 0, 0, 0);
        }
        __syncthreads();
    }
    #pragma unroll
    for (int j = 0; j < 2; ++j) {
        int n = n0 + wn + j * 16 + l15;
        float bv = bias[n];
        #pragma unroll
        for (int i = 0; i < 4; ++i) {
            int mbase = m0 + wm + i * 16 + g * 4;
            #pragma unroll
            for (int r = 0; r < 4; ++r)
                C[(size_t)(mbase + r) * ldc + n] = acc[i][j][r] + bv;
        }
    }
}

// ---------------------------------------------------------------------------
// QKV GEMM with scatter epilogue (unchanged from round 7):
//   Q -> Qd dense; K,V -> fragment-packed pkK/pkV.
// ---------------------------------------------------------------------------
__global__ __launch_bounds__(256) void gemm_qkv(
    const u16* __restrict__ A,            // xb [M][1024]
    const u16* __restrict__ Bt,           // Wqkv_t [3072][1024]
    const float* __restrict__ bias,       // [3072]
    u16* __restrict__ Qd, u16* __restrict__ pkK, u16* __restrict__ pkV) {
    __shared__ u16 As[128 * 64];
    __shared__ u16 Bs[128 * 64];
    const int K = D_MODEL;
    int m0 = blockIdx.x * 128, n0 = blockIdx.y * 128;
    int tid = threadIdx.x;
    int w = tid >> 6, lane = tid & 63, l15 = lane & 15, g = lane >> 4;
    int wm = (w & 1) * 64, wn = (w >> 1) * 64;
    int srow = w * 8 + (lane >> 3);
    int sk8  = lane & 7;

    f32x4 acc[4][4] = {};
    for (int kt = 0; kt < K; kt += 64) {
        #pragma unroll
        for (int p = 0; p < 4; ++p) {
            int row = p * 32 + srow;
            int k8 = sk8 ^ (row & 7);
            async_ld16(&As[p * 2048 + w * 512],
                       A + (size_t)(m0 + row) * K + kt + k8 * 8);
            async_ld16(&Bs[p * 2048 + w * 512],
                       Bt + (size_t)(n0 + row) * K + kt + k8 * 8);
        }
        __syncthreads();
        #pragma unroll
        for (int kk = 0; kk < 2; ++kk) {
            bf16x8 af[4], bf_[4];
            int s8 = ((kk << 2) | g) ^ (l15 & 7);
            #pragma unroll
            for (int i = 0; i < 4; ++i) {
                af[i]  = *(const bf16x8*)&As[(wm + i * 16 + l15) * 64 + s8 * 8];
                bf_[i] = *(const bf16x8*)&Bs[(wn + i * 16 + l15) * 64 + s8 * 8];
            }
            #pragma unroll
            for (int i = 0; i < 4; ++i)
                #pragma unroll
                for (int j = 0; j < 4; ++j)
                    acc[i][j] = __builtin_amdgcn_mfma_f32_16x16x32_bf16(
                        af[i], bf_[j], acc[i][j], 0, 0, 0);
        }
        __syncthreads();
    }
    #pragma unroll
    for (int j = 0; j < 4; ++j) {
        int n = n0 + wn + j * 16 + l15;
        float bv = bias[n];
        int region = n >> 10;            // wave-uniform (64-aligned run)
        int hd = n & 1023;
        int h = hd >> 6, d = hd & 63;
        #pragma unroll
        for (int i = 0; i < 4; ++i) {
            #pragma unroll
            for (int r = 0; r < 4; ++r) {
                int m = m0 + wm + i * 16 + g * 4 + r;
                u16 vb = f2bf(acc[i][j][r] + bv);
                int b = m >> 11, s = m & 2047;
                int t = s >> 6, kap = s & 63;
                if (region == 0) {
                    Qd[(size_t)m * 1024 + hd] = vb;
                } else if (region == 1) {
                    int bh = b * 16 + h;
                    int nb = kap >> 4, lk = kap & 15;
                    int kk = d >> 5, gk = (d >> 3) & 3, jk = d & 7;
                    pkK[(size_t)(bh * 32 + t) * 4096 +
                        ((nb * 2 + kk) * 64 + gk * 16 + lk) * 8 + jk] = vb;
                } else {
                    int bh = b * 16 + h;
                    int kk = kap >> 5, gv = (kap >> 3) & 3, jv = kap & 7;
                    int nb = d >> 4, lv = d & 15;
                    pkV[(size_t)(bh * 32 + t) * 4096 +
                        ((nb * 2 + kk) * 64 + gv * 16 + lv) * 8 + jv] = vb;
                }
            }
        }
    }
}

// ---------------------------------------------------------------------------
// Flash attention, causal, no-max softmax, wave-split-K + causal pairing
// (unchanged from round 7). grid = (B*NH, 16).
// ---------------------------------------------------------------------------
__global__ __launch_bounds__(256) void attn_flash(
    u16* __restrict__ Qd, const u16* __restrict__ pkK,
    const u16* __restrict__ pkV) {
    __shared__ __align__(16) char smemraw[18432 + 256];
    u16 (*Pt)[32][72] = (u16(*)[32][72])smemraw;    // per-wave [32 q][72]
    float* Om = (float*)smemraw;                     // post-loop: [64 q][65]
    float* Lm = (float*)(smemraw + 18432);           // post-loop: [64 q]

    int bh = blockIdx.x, b = bh >> 4, h = bh & 15;
    int tid = threadIdx.x;
    int w = tid >> 6, lane = tid & 63, l15 = lane & 15, g = lane >> 4;
    int wq = w >> 1, wk = w & 1;

    const u16* Kb = pkK + (size_t)bh * 32 * 4096;
    const u16* Vb = pkV + (size_t)bh * 32 * 4096;
    u16* Qbase = Qd + (size_t)b * SEQ * 1024 + h * DH;

    int qts[2] = {31 - (int)blockIdx.y, (int)blockIdx.y};

    #pragma unroll
    for (int qi = 0; qi < 2; ++qi) {
        int qt = qts[qi];
        int q0 = qt * 64;

        bf16x8 qfrag[2][2];
        #pragma unroll
        for (int st = 0; st < 2; ++st) {
            const u16* qp = Qbase + (size_t)(q0 + wq * 32 + st * 16 + l15) * 1024 + g * 8;
            bf16x8 a = *(const bf16x8*)qp;
            bf16x8 c = *(const bf16x8*)(qp + 32);
            #pragma unroll
            for (int jj = 0; jj < 8; ++jj) {
                a[jj] = (__bf16)((float)a[jj] * 0.125f);
                c[jj] = (__bf16)((float)c[jj] * 0.125f);
            }
            qfrag[st][0] = a; qfrag[st][1] = c;
        }

        f32x4 o[2][4] = {};
        float lsum[2][4] = {};

        for (int t = wk; t <= qt; t += 2) {
            const u16* kt = Kb + t * 4096;
            const u16* vt = Vb + t * 4096;
            bf16x8 kf[4][2], vf[4][2];
            #pragma unroll
            for (int nb = 0; nb < 4; ++nb) {
                #pragma unroll
                for (int kk = 0; kk < 2; ++kk) {
                    kf[nb][kk] = *(const bf16x8*)(kt + ((nb * 2 + kk) * 64 + lane) * 8);
                    vf[nb][kk] = *(const bf16x8*)(vt + ((nb * 2 + kk) * 64 + lane) * 8);
                }
            }
            bool diag = (t == qt);
            int k0 = t * 64;

            #pragma unroll
            for (int st = 0; st < 2; ++st) {
                f32x4 s[4] = {};
                #pragma unroll
                for (int nb = 0; nb < 4; ++nb)
                    #pragma unroll
                    for (int kk = 0; kk < 2; ++kk)
                        s[nb] = __builtin_amdgcn_mfma_f32_16x16x32_bf16(
                            qfrag[st][kk], kf[nb][kk], s[nb], 0, 0, 0);

                #pragma unroll
                for (int r = 0; r < 4; ++r) {
                    int qg = q0 + wq * 32 + st * 16 + g * 4 + r;
                    #pragma unroll
                    for (int nb = 0; nb < 4; ++nb) {
                        float p = __expf(s[nb][r]);
                        if (diag && (k0 + nb * 16 + l15) > qg) p = 0.f;
                        lsum[st][r] += p;
                        Pt[w][st * 16 + g * 4 + r][nb * 16 + l15] =
                            (u16)(__float_as_uint(p) >> 16);
                    }
                }

                #pragma unroll
                for (int kk = 0; kk < 2; ++kk) {
                    bf16x8 aP = *(const bf16x8*)&Pt[w][st * 16 + l15][kk * 32 + g * 8];
                    #pragma unroll
                    for (int nb = 0; nb < 4; ++nb)
                        o[st][nb] = __builtin_amdgcn_mfma_f32_16x16x32_bf16(
                            aP, vf[nb][kk], o[st][nb], 0, 0, 0);
                }
            }
        }

        #pragma unroll
        for (int msk = 1; msk < 16; msk <<= 1)
            #pragma unroll
            for (int st = 0; st < 2; ++st)
                #pragma unroll
                for (int r = 0; r < 4; ++r)
                    lsum[st][r] += __shfl_xor(lsum[st][r], msk, 64);

        __syncthreads();
        if (wk == 0) {
            #pragma unroll
            for (int st = 0; st < 2; ++st)
                #pragma unroll
                for (int r = 0; r < 4; ++r) {
                    int qrow = wq * 32 + st * 16 + g * 4 + r;
                    if (l15 == 0) Lm[qrow] = lsum[st][r];
                    #pragma unroll
                    for (int nb = 0; nb < 4; ++nb)
                        Om[qrow * 65 + nb * 16 + l15] = o[st][nb][r];
                }
        }
        __syncthreads();
        if (wk == 1) {
            #pragma unroll
            for (int st = 0; st < 2; ++st)
                #pragma unroll
                for (int r = 0; r < 4; ++r) {
                    int qrow = wq * 32 + st * 16 + g * 4 + r;
                    float inv = 1.f / (lsum[st][r] + Lm[qrow]);
                    u16* op = Qbase + (size_t)(q0 + qrow) * 1024;
                    #pragma unroll
                    for (int nb = 0; nb < 4; ++nb) {
                        float val = (o[st][nb][r] + Om[qrow * 65 + nb * 16 + l15]) * inv;
                        op[nb * 16 + l15] = f2bf(val);
                    }
                }
        }
        __syncthreads();   // protect Pt before next q-tile reuses it
    }
}

// ---------------------------------------------------------------------------
extern "C" void kernel_launch(void* const* d_in, const int* in_sizes, int n_in,
                              void* d_out, int out_size, void* d_ws, size_t ws_size,
                              hipStream_t stream) {
    const float* x     = (const float*)d_in[0];
    const float* qkv_w = (const float*)d_in[1];
    const float* qkv_b = (const float*)d_in[2];
    const float* out_w = (const float*)d_in[3];
    const float* out_b = (const float*)d_in[4];
    float* out = (float*)d_out;

    const int M = BATCH * SEQ;                             // 8192
    u16* Qd     = (u16*)d_ws;                              // [M][1024]      16.8 MB
    u16* pkK    = Qd  + (size_t)M * D_MODEL;               // [64][32][4096] 16.8 MB
    u16* pkV    = pkK + (size_t)64 * 32 * 4096;            //                16.8 MB
    u16* xb     = pkV + (size_t)64 * 32 * 4096;            // [M][1024]      16.8 MB
    u16* Wqkv_t = xb  + (size_t)M * D_MODEL;               // [3072][1024]    6.3 MB
    u16* Wout_t = Wqkv_t + (size_t)3 * D_MODEL * D_MODEL;  // [1024][1024]    2.1 MB

    cvt_bf16<<<(size_t)M * D_MODEL / (256 * 8), 256, 0, stream>>>(x, xb);
    transpose_w<<<dim3(3 * D_MODEL / 32, D_MODEL / 32), dim3(32, 8), 0, stream>>>(
        qkv_w, Wqkv_t, D_MODEL, 3 * D_MODEL);
    transpose_w<<<dim3(D_MODEL / 32, D_MODEL / 32), dim3(32, 8), 0, stream>>>(
        out_w, Wout_t, D_MODEL, D_MODEL);

    // QKV projection with fused scatter into Qd / packed K / packed V
    gemm_qkv<<<dim3(M / 128, 3 * D_MODEL / 128), 256, 0, stream>>>(
        xb, Wqkv_t, qkv_b, Qd, pkK, pkV);

    // paired causal flash attention (in-place on Qd)
    attn_flash<<<dim3(BATCH * NH, SEQ / 64 / 2), 256, 0, stream>>>(Qd, pkK, pkV);

    // output projection: 128x64 tiles -> 1024 blocks (4/CU)
    gemm_bt_n64<<<dim3(M / 128, D_MODEL / 64), 256, 0, stream>>>(
        Qd, D_MODEL, Wout_t, D_MODEL, out_b, out, D_MODEL, D_MODEL);
}